// Round 25
// baseline (495.338 us; speedup 1.0000x reference)
//
#include <hip/hip_runtime.h>
#include <hip/hip_bf16.h>
#include <cstdint>
#include <cstddef>

#define IN_CH 312
#define HID 256

typedef __attribute__((ext_vector_type(8))) short bf16x8;
typedef __attribute__((ext_vector_type(4))) float f32x4;
typedef __attribute__((ext_vector_type(8))) unsigned short ushort8;

__device__ __forceinline__ unsigned short f2bf(float f) {
    union { float f; unsigned u; } v; v.f = f;
    const unsigned r = v.u + 0x7FFFu + ((v.u >> 16) & 1u);  // RNE
    return (unsigned short)(r >> 16);
}
__device__ __forceinline__ float bf2f(unsigned short s) {
    union { unsigned u; float f; } v; v.u = (unsigned)s << 16;
    return v.f;
}
__device__ __forceinline__ void gload_lds16(const void* g, void* l) {
    __builtin_amdgcn_global_load_lds(
        (const __attribute__((address_space(1))) void*)g,
        (__attribute__((address_space(3))) void*)l, 16, 0, 0);
}

// ---------------------------------------------------------------------------
// Index dtype detector (int64 vs int32 edge_index).
// ---------------------------------------------------------------------------
__global__ void detect_idx_kernel(const void* __restrict__ ei, int* __restrict__ flag) {
    if (blockIdx.x == 0 && threadIdx.x == 0) {
        const int* p = (const int*)ei;
        int ok = 1;
        for (int i = 0; i < 64; ++i) ok &= (p[2 * i + 1] == 0);
        *flag = ok;
    }
}
__device__ __forceinline__ long long load_idx(const void* ei, long long i, bool is64) {
    return is64 ? ((const long long*)ei)[i] : (long long)((const int*)ei)[i];
}

// ---------------------------------------------------------------------------
// CSR build (unordered groups): histogram -> atomic group-offset assignment
// -> atomic-cursor fill.
// ---------------------------------------------------------------------------
__global__ void hist_kernel(const void* __restrict__ ei, const int* __restrict__ flag,
                            int* __restrict__ cnt, int E) {
    const int i = blockIdx.x * blockDim.x + threadIdx.x;
    if (i >= E) return;
    const bool is64 = (*flag != 0);
    atomicAdd(&cnt[load_idx(ei, (long long)E + i, is64)], 1);
}

__global__ void offsets_kernel(const int* __restrict__ cnt, int* __restrict__ counter,
                               int* __restrict__ beg, int* __restrict__ cur, int n) {
    const int i = blockIdx.x * blockDim.x + threadIdx.x;
    if (i >= n) return;
    const int b = atomicAdd(counter, cnt[i]);
    beg[i] = b;
    cur[i] = b;
}

__global__ void fill_kernel(const void* __restrict__ ei, const int* __restrict__ flag,
                            int* __restrict__ cur, int* __restrict__ col, int E) {
    const int i = blockIdx.x * blockDim.x + threadIdx.x;
    if (i >= E) return;
    const bool is64 = (*flag != 0);
    const long long s = load_idx(ei, i, is64);
    const long long d = load_idx(ei, (long long)E + i, is64);
    col[atomicAdd(&cur[d], 1)] = (int)s;
}

// ---------------------------------------------------------------------------
// x fp32 [N,312] -> bf16 [N,320]. Separate streaming pass (R23 lesson).
// ---------------------------------------------------------------------------
__global__ void convert_x_kernel(const float* __restrict__ x, unsigned short* __restrict__ xb,
                                 int N) {
    const int tid = blockIdx.x * blockDim.x + threadIdx.x;
    if (tid >= N * 40) return;
    const int row = tid / 40;
    const int c8 = (tid % 40) * 8;
    ushort8 o;
    if (c8 < IN_CH) {
        const float4 v0 = *(const float4*)(x + (size_t)row * IN_CH + c8);
        const float4 v1 = *(const float4*)(x + (size_t)row * IN_CH + c8 + 4);
        o[0] = f2bf(v0.x); o[1] = f2bf(v0.y); o[2] = f2bf(v0.z); o[3] = f2bf(v0.w);
        o[4] = f2bf(v1.x); o[5] = f2bf(v1.y); o[6] = f2bf(v1.z); o[7] = f2bf(v1.w);
    } else {
        o = (ushort8)0;
    }
    *(ushort8*)(xb + (size_t)row * 320 + c8) = o;
}

// WcatT[c][k] = (c<256 ? Wl[k][c] : Wr[k][c-256]), bf16, k >= K zero-padded.
__global__ void convert_w_kernel(const float* __restrict__ Wl, const float* __restrict__ Wr,
                                 unsigned short* __restrict__ wt, int K, int Kpad) {
    const int tid = blockIdx.x * blockDim.x + threadIdx.x;
    if (tid >= 512 * Kpad) return;
    const int c = tid / Kpad;
    const int k = tid % Kpad;
    float v = 0.f;
    if (k < K) v = (c < 256) ? Wl[(size_t)k * 256 + c] : Wr[(size_t)k * 256 + (c - 256)];
    wt[(size_t)c * Kpad + k] = f2bf(v);
}

// ---------------------------------------------------------------------------
// Depth-2 counted-vmcnt MFMA GEMM (R22 proven structure; R25 only changes
// the Y epilogue addressing to halved layout [2][M][128] for the
// channel-split gather; chunk cb (multiple of 32) never straddles 128).
// Race law (R15-R21): barrier B drains lgkmcnt before signaling.
// Per iter t: vmcnt(3); s_barrier (A); compute(t); lgkmcnt(0)+s_barrier (B);
// stage(t+2). Prologue tile order pinned.
// Grid (M/128, 2): y=0 -> Y halves; y=1 -> Z bf16 rows of ZSTR ushorts
// (+bias; caller bakes any base offset into Z).
// ---------------------------------------------------------------------------
template <int KPAD, int ZSTR>
__global__ __launch_bounds__(512) void mfma_gemm_kernel(
    const unsigned short* __restrict__ A,   // [M][KPAD] bf16
    const unsigned short* __restrict__ WT,  // [512][KPAD] bf16
    const float* __restrict__ bias,         // [256]
    unsigned short* __restrict__ Y,         // [2][M][128] bf16 halves
    unsigned short* __restrict__ Z,         // [M] rows of ZSTR ushorts, bf16
    int M)
{
    constexpr int NS = KPAD / 32;
    __shared__ __align__(16) char smem[49152];

    const int tid  = (int)threadIdx.x;
    const int lane = tid & 63;
    const int wid  = tid >> 6;
    const int wr = wid >> 1, wc = wid & 1;
    const int r0 = blockIdx.x * 128;
    const int c0 = blockIdx.y * 256;        // 0 -> Y, 256 -> Z

    const int lrow = lane & 15;
    const int kgrp = lane >> 4;

    f32x4 acc[2][8];
    #pragma unroll
    for (int i = 0; i < 2; ++i)
        #pragma unroll
        for (int j = 0; j < 8; ++j) acc[i][j] = (f32x4)0.f;

    const int glrow = lane >> 2;
    const int glc   = (lane & 3) ^ ((glrow >> 1) & 3);

    auto stage = [&](int t, int b) {
        char* ab = smem + b * 8192;
        char* bb = smem + 16384 + b * 16384;
        const int kb = t * 32;
        #pragma unroll
        for (int j = 0; j < 2; ++j) {
            const int ld = wid * 2 + j;
            const int row = ld * 16 + glrow;
            gload_lds16(WT + (size_t)(c0 + row) * KPAD + kb + glc * 8,
                        bb + ld * 1024);
        }
        const int arow = wid * 16 + glrow;
        const int gr = min(r0 + arow, M - 1);
        gload_lds16(A + (size_t)gr * KPAD + kb + glc * 8, ab + wid * 1024);
    };
    auto compute = [&](int b) {
        const char* ab = smem + b * 8192;
        const char* bb = smem + 16384 + b * 16384;
        bf16x8 af[2], bg[8];
        #pragma unroll
        for (int f = 0; f < 2; ++f) {
            const int arow = wr * 32 + f * 16 + lrow;
            const int p = kgrp ^ ((arow >> 1) & 3);
            af[f] = *(const bf16x8*)(ab + arow * 64 + p * 16);
        }
        #pragma unroll
        for (int fn = 0; fn < 8; ++fn) {
            const int brow = wc * 128 + fn * 16 + lrow;
            const int p = kgrp ^ ((brow >> 1) & 3);
            bg[fn] = *(const bf16x8*)(bb + brow * 64 + p * 16);
        }
        #pragma unroll
        for (int fn = 0; fn < 8; ++fn) {
            acc[0][fn] = __builtin_amdgcn_mfma_f32_16x16x32_bf16(af[0], bg[fn], acc[0][fn], 0, 0, 0);
            acc[1][fn] = __builtin_amdgcn_mfma_f32_16x16x32_bf16(af[1], bg[fn], acc[1][fn], 0, 0, 0);
        }
    };

    // prologue: stage tiles 0 and 1, tile order pinned
    stage(0, 0);
    __builtin_amdgcn_sched_barrier(0);
    asm volatile("" ::: "memory");
    stage(1, 1);
    __builtin_amdgcn_sched_barrier(0);
    asm volatile("" ::: "memory");

    #pragma unroll
    for (int t = 0; t < NS; ++t) {
        const int b = t & 1;
        if (t + 1 < NS) {
            asm volatile("s_waitcnt vmcnt(3)" ::: "memory");
        } else {
            asm volatile("s_waitcnt vmcnt(0)" ::: "memory");
        }
        asm volatile("s_barrier" ::: "memory");               // barrier A
        __builtin_amdgcn_sched_barrier(0);
        compute(b);
        if (t + 2 < NS) {
            asm volatile("s_waitcnt lgkmcnt(0)\n\ts_barrier" ::: "memory");  // barrier B
            stage(t + 2, b);
        }
    }

    // epilogue: bf16 via LDS transpose, two 64-row halves.
    const bool isY = (c0 == 0);
    const int cloc = wc * 128 + (lane & 15);

    constexpr int CST = 264;
    short* c_lds = (short*)smem;
    float bv4[8];
    #pragma unroll
    for (int fn = 0; fn < 8; ++fn)
        bv4[fn] = isY ? 0.f : bias[cloc + fn * 16];
    #pragma unroll
    for (int h = 0; h < 2; ++h) {
        __syncthreads();
        if ((wr >> 1) == h) {
            const int lr0 = (wr & 1) * 32 + (lane >> 4) * 4;
            #pragma unroll
            for (int fm = 0; fm < 2; ++fm)
                #pragma unroll
                for (int fn = 0; fn < 8; ++fn)
                    #pragma unroll
                    for (int r = 0; r < 4; ++r)
                        c_lds[(lr0 + fm * 16 + r) * CST + cloc + fn * 16] =
                            (short)f2bf(acc[fm][fn][r] + bv4[fn]);
        }
        __syncthreads();
        const int row = tid >> 3;             // 0..63
        const int cb  = (tid & 7) * 32;       // 0,32,..,224
        const int gr  = r0 + h * 64 + row;
        if (gr < M) {
            unsigned short* dst = isY
                ? (Y + (size_t)(cb >> 7) * ((size_t)M * 128) + (size_t)gr * 128 + (cb & 127))
                : (Z + (size_t)gr * ZSTR + cb);
            #pragma unroll
            for (int j = 0; j < 4; ++j)
                *(ushort8*)(dst + j * 8) =
                    *(const ushort8*)&c_lds[row * CST + cb + j * 8];
        }
    }
}

// ---------------------------------------------------------------------------
// Channel-split gather (R25): one 128-ch HALF per dispatch, run halves
// SEQUENTIALLY so the random-read footprint (Y half = 25.6MB, 10% of L3)
// stays L3-resident -> re-reads become L3 hits instead of HBM fetches.
// Lane owns 2 channels (ushort2, 64x4B = 256B/edge, coalesced).
// Z bf16 rows of ZSTR ushorts (base pre-offset by caller); z read hoisted.
// LAYER1: relu, write bf16 h-half. else: write fp32 out-half in place
// (out floats half*128.. occupy bytes disjoint from (or read-before-write
// within the same wave of) the z2 region at row bytes 512..1023).
// ---------------------------------------------------------------------------
template <bool LAYER1>
__global__ void gather_agg_kernel(const unsigned short* __restrict__ Y,
                                  const int* __restrict__ beg_arr,
                                  const int* __restrict__ cnt,
                                  const int* __restrict__ col,
                                  const unsigned short* Z,
                                  void* OUT, int N, int half)
{
    const long long gw = ((long long)blockIdx.x * blockDim.x + threadIdx.x) >> 6;
    if (gw >= N) return;
    const int w = (int)gw;
    const int lane = threadIdx.x & 63;
    const int c2 = lane * 2;                    // channel pair within half
    const int beg = beg_arr[w];
    const int deg = cnt[w];
    const int end = beg + deg;

    const unsigned short* yh = Y + (size_t)half * ((size_t)N * 128);

    // z load hoisted: read before any store to the aliased region
    const size_t zstr = LAYER1 ? 256 : 512;
    const ushort2 zb = *(const ushort2*)(Z + (size_t)w * zstr + half * 128 + c2);
    const float zx = bf2f(zb.x), zy = bf2f(zb.y);

    float a0x = 0.f, a0y = 0.f, a1x = 0.f, a1y = 0.f;
    int e = beg;
    for (; e + 3 < end; e += 4) {
        const int s0 = col[e], s1 = col[e + 1], s2 = col[e + 2], s3 = col[e + 3];
        const ushort2 v0 = *(const ushort2*)(yh + (size_t)s0 * 128 + c2);
        const ushort2 v1 = *(const ushort2*)(yh + (size_t)s1 * 128 + c2);
        const ushort2 v2 = *(const ushort2*)(yh + (size_t)s2 * 128 + c2);
        const ushort2 v3 = *(const ushort2*)(yh + (size_t)s3 * 128 + c2);
        a0x += bf2f(v0.x) + bf2f(v1.x);  a1x += bf2f(v2.x) + bf2f(v3.x);
        a0y += bf2f(v0.y) + bf2f(v1.y);  a1y += bf2f(v2.y) + bf2f(v3.y);
    }
    if (e + 1 < end) {
        const int s0 = col[e], s1 = col[e + 1];
        const ushort2 v0 = *(const ushort2*)(yh + (size_t)s0 * 128 + c2);
        const ushort2 v1 = *(const ushort2*)(yh + (size_t)s1 * 128 + c2);
        a0x += bf2f(v0.x) + bf2f(v1.x);
        a0y += bf2f(v0.y) + bf2f(v1.y);
        e += 2;
    }
    if (e < end) {
        const ushort2 v0 = *(const ushort2*)(yh + (size_t)col[e] * 128 + c2);
        a0x += bf2f(v0.x); a0y += bf2f(v0.y);
    }

    const float inv = 1.0f / fmaxf((float)deg, 1.0f);
    float ox = (a0x + a1x) * inv + zx;
    float oy = (a0y + a1y) * inv + zy;
    if (LAYER1) {
        ox = fmaxf(ox, 0.f); oy = fmaxf(oy, 0.f);
        ushort2 ob; ob.x = f2bf(ox); ob.y = f2bf(oy);
        *(ushort2*)((unsigned short*)OUT + (size_t)w * 256 + half * 128 + c2) = ob;
    } else {
        float2 of; of.x = ox; of.y = oy;
        *(float2*)((float*)OUT + (size_t)w * 256 + half * 128 + c2) = of;
    }
}

// ---------------------------------------------------------------------------
extern "C" void kernel_launch(void* const* d_in, const int* in_sizes, int n_in,
                              void* d_out, int out_size, void* d_ws, size_t ws_size,
                              hipStream_t stream) {
    const float* x   = (const float*)d_in[0];
    const void*  ei  = d_in[1];
    const float* W1l = (const float*)d_in[2];
    const float* b1  = (const float*)d_in[3];
    const float* W1r = (const float*)d_in[4];
    const float* W2l = (const float*)d_in[5];
    const float* b2  = (const float*)d_in[6];
    const float* W2r = (const float*)d_in[7];

    const int N = in_sizes[0] / IN_CH;  // 100000
    const int E = in_sizes[1] / 2;      // 1000000

    char* ws = (char*)d_ws;
    size_t off = 0;
    auto alloc = [&](size_t bytes) {
        void* p = ws + off;
        off = (off + bytes + 255) & ~(size_t)255;
        return p;
    };
    int* flag    = (int*)alloc(4);
    int* cnt     = (int*)alloc((size_t)(N + 1) * 4);
    int* counter = cnt + N;
    int* beg     = (int*)alloc((size_t)N * 4);
    int* cur     = (int*)alloc((size_t)N * 4);
    int* col     = (int*)alloc((size_t)E * 4);
    unsigned short* wt1 = (unsigned short*)alloc((size_t)512 * 320 * 2);
    unsigned short* wt2 = (unsigned short*)alloc((size_t)512 * 256 * 2);
    unsigned short* xb  = (unsigned short*)alloc((size_t)N * 320 * 2);  // x bf16; hb reuses
    unsigned short* y   = (unsigned short*)alloc((size_t)N * 256 * 2);  // y halves [2][N][128]

    unsigned short* hb = xb;  // h bf16 [N][256]; xb dead after layer-1 GEMM

    float* out = (float*)d_out;
    unsigned short* z1 = (unsigned short*)d_out;        // layer-1 z, dense 256/row
    unsigned short* z2 = (unsigned short*)d_out + 256;  // layer-2 z, SECOND 512B of
                                                        // each 1KB row, stride 512

    // ---- CSR build (by dst, unordered groups) ----
    hipMemsetAsync(cnt, 0, (size_t)(N + 1) * 4, stream);
    detect_idx_kernel<<<1, 64, 0, stream>>>(ei, flag);
    hist_kernel<<<(E + 255) / 256, 256, 0, stream>>>(ei, flag, cnt, E);
    offsets_kernel<<<(N + 255) / 256, 256, 0, stream>>>(cnt, counter, beg, cur, N);
    fill_kernel<<<(E + 255) / 256, 256, 0, stream>>>(ei, flag, cur, col, E);

    // ---- conversions ----
    convert_x_kernel<<<(N * 40 + 255) / 256, 256, 0, stream>>>(x, xb, N);
    convert_w_kernel<<<(512 * 320 + 255) / 256, 256, 0, stream>>>(W1l, W1r, wt1, IN_CH, 320);
    convert_w_kernel<<<(512 * 256 + 255) / 256, 256, 0, stream>>>(W2l, W2r, wt2, HID, 256);

    const dim3 ggrid((N + 127) / 128, 2);
    const int gblocks = (N + 3) / 4;

    // ---- layer 1: y=x@W1l (halved bf16), z1=x@W1r+b1 ; h=relu(mean+z1) ----
    mfma_gemm_kernel<320, 256><<<ggrid, 512, 0, stream>>>(xb, wt1, b1, y, z1, N);
    gather_agg_kernel<true><<<gblocks, 256, 0, stream>>>(y, beg, cnt, col, z1, hb, N, 0);
    gather_agg_kernel<true><<<gblocks, 256, 0, stream>>>(y, beg, cnt, col, z1, hb, N, 1);

    // ---- layer 2: y=h@W2l (halved), z2=h@W2r+b2 ; out = mean+z2 (in place) ----
    mfma_gemm_kernel<256, 512><<<ggrid, 512, 0, stream>>>(hb, wt2, b2, y, z2, N);
    gather_agg_kernel<false><<<gblocks, 256, 0, stream>>>(y, beg, cnt, col, z2, out, N, 0);
    gather_agg_kernel<false><<<gblocks, 256, 0, stream>>>(y, beg, cnt, col, z2, out, N, 1);
}

// Round 26
// 460.376 us; speedup vs baseline: 1.0759x; 1.0759x over previous
//
#include <hip/hip_runtime.h>
#include <hip/hip_bf16.h>
#include <cstdint>
#include <cstddef>

#define IN_CH 312
#define HID 256

typedef __attribute__((ext_vector_type(8))) short bf16x8;
typedef __attribute__((ext_vector_type(4))) float f32x4;
typedef __attribute__((ext_vector_type(8))) unsigned short ushort8;

__device__ __forceinline__ unsigned short f2bf(float f) {
    union { float f; unsigned u; } v; v.f = f;
    const unsigned r = v.u + 0x7FFFu + ((v.u >> 16) & 1u);  // RNE
    return (unsigned short)(r >> 16);
}
__device__ __forceinline__ float bf2f(unsigned short s) {
    union { unsigned u; float f; } v; v.u = (unsigned)s << 16;
    return v.f;
}
__device__ __forceinline__ void gload_lds16(const void* g, void* l) {
    __builtin_amdgcn_global_load_lds(
        (const __attribute__((address_space(1))) void*)g,
        (__attribute__((address_space(3))) void*)l, 16, 0, 0);
}

// ---------------------------------------------------------------------------
// Index dtype detector (int64 vs int32 edge_index).
// ---------------------------------------------------------------------------
__global__ void detect_idx_kernel(const void* __restrict__ ei, int* __restrict__ flag) {
    if (blockIdx.x == 0 && threadIdx.x == 0) {
        const int* p = (const int*)ei;
        int ok = 1;
        for (int i = 0; i < 64; ++i) ok &= (p[2 * i + 1] == 0);
        *flag = ok;
    }
}
__device__ __forceinline__ long long load_idx(const void* ei, long long i, bool is64) {
    return is64 ? ((const long long*)ei)[i] : (long long)((const int*)ei)[i];
}

// ---------------------------------------------------------------------------
// CSR build (unordered groups): histogram -> atomic group-offset assignment
// -> atomic-cursor fill. Group membership is exact; placement order is
// atomic-timing dependent (tolerated; validated across many rounds).
// ---------------------------------------------------------------------------
__global__ void hist_kernel(const void* __restrict__ ei, const int* __restrict__ flag,
                            int* __restrict__ cnt, int E) {
    const int i = blockIdx.x * blockDim.x + threadIdx.x;
    if (i >= E) return;
    const bool is64 = (*flag != 0);
    atomicAdd(&cnt[load_idx(ei, (long long)E + i, is64)], 1);
}

__global__ void offsets_kernel(const int* __restrict__ cnt, int* __restrict__ counter,
                               int* __restrict__ beg, int* __restrict__ cur, int n) {
    const int i = blockIdx.x * blockDim.x + threadIdx.x;
    if (i >= n) return;
    const int b = atomicAdd(counter, cnt[i]);
    beg[i] = b;
    cur[i] = b;
}

__global__ void fill_kernel(const void* __restrict__ ei, const int* __restrict__ flag,
                            int* __restrict__ cur, int* __restrict__ col, int E) {
    const int i = blockIdx.x * blockDim.x + threadIdx.x;
    if (i >= E) return;
    const bool is64 = (*flag != 0);
    const long long s = load_idx(ei, i, is64);
    const long long d = load_idx(ei, (long long)E + i, is64);
    col[atomicAdd(&cur[d], 1)] = (int)s;
}

// ---------------------------------------------------------------------------
// x fp32 [N,312] -> bf16 [N,320] (cols 312..319 zero).
// Kept SEPARATE from the GEMM: R23 proved in-loop conversion sits on the
// barrier-locked critical path and costs more (+17us) than this streaming
// pass (~28us at ~86% HBM efficiency with full TLP).
// ---------------------------------------------------------------------------
__global__ void convert_x_kernel(const float* __restrict__ x, unsigned short* __restrict__ xb,
                                 int N) {
    const int tid = blockIdx.x * blockDim.x + threadIdx.x;
    if (tid >= N * 40) return;
    const int row = tid / 40;
    const int c8 = (tid % 40) * 8;
    ushort8 o;
    if (c8 < IN_CH) {
        const float4 v0 = *(const float4*)(x + (size_t)row * IN_CH + c8);
        const float4 v1 = *(const float4*)(x + (size_t)row * IN_CH + c8 + 4);
        o[0] = f2bf(v0.x); o[1] = f2bf(v0.y); o[2] = f2bf(v0.z); o[3] = f2bf(v0.w);
        o[4] = f2bf(v1.x); o[5] = f2bf(v1.y); o[6] = f2bf(v1.z); o[7] = f2bf(v1.w);
    } else {
        o = (ushort8)0;
    }
    *(ushort8*)(xb + (size_t)row * 320 + c8) = o;
}

// WcatT[c][k] = (c<256 ? Wl[k][c] : Wr[k][c-256]), bf16, k >= K zero-padded.
__global__ void convert_w_kernel(const float* __restrict__ Wl, const float* __restrict__ Wr,
                                 unsigned short* __restrict__ wt, int K, int Kpad) {
    const int tid = blockIdx.x * blockDim.x + threadIdx.x;
    if (tid >= 512 * Kpad) return;
    const int c = tid / Kpad;
    const int k = tid % Kpad;
    float v = 0.f;
    if (k < K) v = (c < 256) ? Wl[(size_t)k * 256 + c] : Wr[(size_t)k * 256 + (c - 256)];
    wt[(size_t)c * Kpad + k] = f2bf(v);
}

// ---------------------------------------------------------------------------
// Depth-2 counted-vmcnt MFMA GEMM (R22 proven structure).
// Race lesson (R15-R21): a hand-rolled s_barrier in a double-buffered loop
// MUST drain lgkmcnt before signaling when the other side re-writes LDS
// this wave just read (barrier B below). __syncthreads does it implicitly.
// ALL staged ops are global_load_lds (3/wave/tile): vmcnt(3) steady state.
// Per iter t: vmcnt(3); s_barrier (A); compute(t); lgkmcnt(0)+s_barrier (B);
// stage(t+2). Prologue tile order pinned (sched_barrier + asm fence).
// Tile 128x256, BK=32, 8 waves, A bf16 [M][KPAD] (x pre-converted).
// LDS 48KB. Swizzle chunk ^= ((row>>1)&3) (conflict-free, R14).
// Grid (M/128, 2): y=0 -> Y bf16 [M][256]; y=1 -> Z bf16 rows of ZSTR
// ushorts (+bias). Layer1 ZSTR=256; layer2 ZSTR=512 (z2 in d_out rows).
// ---------------------------------------------------------------------------
template <int KPAD, int ZSTR>
__global__ __launch_bounds__(512) void mfma_gemm_kernel(
    const unsigned short* __restrict__ A,   // [M][KPAD] bf16
    const unsigned short* __restrict__ WT,  // [512][KPAD] bf16
    const float* __restrict__ bias,         // [256]
    unsigned short* __restrict__ Y,         // [M][256] bf16
    unsigned short* __restrict__ Z,         // [M] rows of ZSTR ushorts, bf16
    int M)
{
    constexpr int NS = KPAD / 32;  // K-steps (10 or 8)
    __shared__ __align__(16) char smem[49152];
    // abuf[b] = smem + b*8192 (128 x 64B); bbuf[b] = smem + 16384 + b*16384.

    const int tid  = (int)threadIdx.x;
    const int lane = tid & 63;
    const int wid  = tid >> 6;              // 0..7
    const int wr = wid >> 1, wc = wid & 1;  // 4 wave-rows x 2 wave-cols
    const int r0 = blockIdx.x * 128;
    const int c0 = blockIdx.y * 256;        // 0 -> Y, 256 -> Z

    const int lrow = lane & 15;
    const int kgrp = lane >> 4;             // 0..3 (logical 16B chunk)

    f32x4 acc[2][8];
    #pragma unroll
    for (int i = 0; i < 2; ++i)
        #pragma unroll
        for (int j = 0; j < 8; ++j) acc[i][j] = (f32x4)0.f;

    // gload geometry: wave-load = 1KB = 16 rows x 64B.
    const int glrow = lane >> 2;
    const int glc   = (lane & 3) ^ ((glrow >> 1) & 3);

    auto stage = [&](int t, int b) {  // 3 gloads per wave, fixed issue order
        char* ab = smem + b * 8192;
        char* bb = smem + 16384 + b * 16384;
        const int kb = t * 32;
        #pragma unroll
        for (int j = 0; j < 2; ++j) {
            const int ld = wid * 2 + j;
            const int row = ld * 16 + glrow;
            gload_lds16(WT + (size_t)(c0 + row) * KPAD + kb + glc * 8,
                        bb + ld * 1024);
        }
        const int arow = wid * 16 + glrow;
        const int gr = min(r0 + arow, M - 1);
        gload_lds16(A + (size_t)gr * KPAD + kb + glc * 8, ab + wid * 1024);
    };
    auto compute = [&](int b) {
        const char* ab = smem + b * 8192;
        const char* bb = smem + 16384 + b * 16384;
        bf16x8 af[2], bg[8];
        #pragma unroll
        for (int f = 0; f < 2; ++f) {
            const int arow = wr * 32 + f * 16 + lrow;
            const int p = kgrp ^ ((arow >> 1) & 3);
            af[f] = *(const bf16x8*)(ab + arow * 64 + p * 16);
        }
        #pragma unroll
        for (int fn = 0; fn < 8; ++fn) {
            const int brow = wc * 128 + fn * 16 + lrow;
            const int p = kgrp ^ ((brow >> 1) & 3);
            bg[fn] = *(const bf16x8*)(bb + brow * 64 + p * 16);
        }
        #pragma unroll
        for (int fn = 0; fn < 8; ++fn) {
            acc[0][fn] = __builtin_amdgcn_mfma_f32_16x16x32_bf16(af[0], bg[fn], acc[0][fn], 0, 0, 0);
            acc[1][fn] = __builtin_amdgcn_mfma_f32_16x16x32_bf16(af[1], bg[fn], acc[1][fn], 0, 0, 0);
        }
    };

    // ---- prologue: stage tiles 0 and 1, tile order pinned ----
    stage(0, 0);
    __builtin_amdgcn_sched_barrier(0);
    asm volatile("" ::: "memory");
    stage(1, 1);
    __builtin_amdgcn_sched_barrier(0);
    asm volatile("" ::: "memory");

    // ---- depth-2 counted-vmcnt main loop (fully unrolled) ----
    #pragma unroll
    for (int t = 0; t < NS; ++t) {
        const int b = t & 1;
        if (t + 1 < NS) {
            asm volatile("s_waitcnt vmcnt(3)" ::: "memory");  // tile t landed
        } else {
            asm volatile("s_waitcnt vmcnt(0)" ::: "memory");  // last tile
        }
        asm volatile("s_barrier" ::: "memory");               // barrier A
        __builtin_amdgcn_sched_barrier(0);
        compute(b);
        if (t + 2 < NS) {
            // barrier B: drain this wave's ds_reads into registers BEFORE
            // signaling, so no wave can restage buf b while reads in flight.
            asm volatile("s_waitcnt lgkmcnt(0)\n\ts_barrier" ::: "memory");
            stage(t + 2, b);                                  // in flight 1 iter
        }
    }

    // epilogue: Y and Z both bf16 via LDS transpose, two 64-row halves.
    // C/D layout: col=lane&15, row=(lane>>4)*4+reg  [m89]
    const bool isY = (c0 == 0);
    const int cloc = wc * 128 + (lane & 15);  // 0..255 within tile

    constexpr int CST = 264;  // shorts/row: 528B, keeps 16B align
    short* c_lds = (short*)smem;
    float bv4[8];
    #pragma unroll
    for (int fn = 0; fn < 8; ++fn)
        bv4[fn] = isY ? 0.f : bias[cloc + fn * 16];
    #pragma unroll
    for (int h = 0; h < 2; ++h) {
        __syncthreads();
        if ((wr >> 1) == h) {
            const int lr0 = (wr & 1) * 32 + (lane >> 4) * 4;
            #pragma unroll
            for (int fm = 0; fm < 2; ++fm)
                #pragma unroll
                for (int fn = 0; fn < 8; ++fn)
                    #pragma unroll
                    for (int r = 0; r < 4; ++r)
                        c_lds[(lr0 + fm * 16 + r) * CST + cloc + fn * 16] =
                            (short)f2bf(acc[fm][fn][r] + bv4[fn]);
        }
        __syncthreads();
        const int row = tid >> 3;             // 0..63
        const int cb  = (tid & 7) * 32;       // 0..224
        const int gr  = r0 + h * 64 + row;
        if (gr < M) {
            unsigned short* dst = isY
                ? (Y + (size_t)gr * 256 + cb)
                : (Z + (size_t)gr * ZSTR + cb);
            #pragma unroll
            for (int j = 0; j < 4; ++j)
                *(ushort8*)(dst + j * 8) =
                    *(const ushort8*)&c_lds[row * CST + cb + j * 8];
        }
    }
}

// ---------------------------------------------------------------------------
// Gather aggregation over bf16 y: out[i] = act( mean_{e}(y[col[e]]) + Z[i] ).
// Z/OUT may alias d_out (layer 2): NOT restrict-qualified; z loaded first
// (program order preserved by the compiler under may-alias).
// LAYER1: ZSTR=256, act=relu, write bf16 h (ws).
// else:   ZSTR=512 (z2 = first 512B of each 1KB d_out row), write fp32
//         d_out in place (same wave, read precedes write, rows disjoint).
// ---------------------------------------------------------------------------
template <bool LAYER1>
__global__ void gather_agg_kernel(const unsigned short* __restrict__ Y,
                                  const int* __restrict__ beg_arr,
                                  const int* __restrict__ cnt,
                                  const int* __restrict__ col,
                                  const unsigned short* Z,
                                  void* OUT, int N)
{
    const long long gw = ((long long)blockIdx.x * blockDim.x + threadIdx.x) >> 6;
    if (gw >= N) return;
    const int w = (int)gw;
    const int lane = threadIdx.x & 63;
    const int c4 = lane * 4;
    const int beg = beg_arr[w];
    const int deg = cnt[w];
    const int end = beg + deg;

    // z load hoisted: read before any store to the aliased region
    const size_t zstr = LAYER1 ? 256 : 512;
    const ushort4 zb = *(const ushort4*)(Z + (size_t)w * zstr + c4);
    const float4 z = make_float4(bf2f(zb.x), bf2f(zb.y), bf2f(zb.z), bf2f(zb.w));

    float4 a0 = make_float4(0.f, 0.f, 0.f, 0.f);
    float4 a1 = make_float4(0.f, 0.f, 0.f, 0.f);
    int e = beg;
    for (; e + 3 < end; e += 4) {
        const int s0 = col[e], s1 = col[e + 1], s2 = col[e + 2], s3 = col[e + 3];
        const ushort4 v0 = *(const ushort4*)(Y + (size_t)s0 * 256 + c4);
        const ushort4 v1 = *(const ushort4*)(Y + (size_t)s1 * 256 + c4);
        const ushort4 v2 = *(const ushort4*)(Y + (size_t)s2 * 256 + c4);
        const ushort4 v3 = *(const ushort4*)(Y + (size_t)s3 * 256 + c4);
        a0.x += bf2f(v0.x) + bf2f(v1.x);  a1.x += bf2f(v2.x) + bf2f(v3.x);
        a0.y += bf2f(v0.y) + bf2f(v1.y);  a1.y += bf2f(v2.y) + bf2f(v3.y);
        a0.z += bf2f(v0.z) + bf2f(v1.z);  a1.z += bf2f(v2.z) + bf2f(v3.z);
        a0.w += bf2f(v0.w) + bf2f(v1.w);  a1.w += bf2f(v2.w) + bf2f(v3.w);
    }
    if (e + 1 < end) {
        const int s0 = col[e], s1 = col[e + 1];
        const ushort4 v0 = *(const ushort4*)(Y + (size_t)s0 * 256 + c4);
        const ushort4 v1 = *(const ushort4*)(Y + (size_t)s1 * 256 + c4);
        a0.x += bf2f(v0.x) + bf2f(v1.x);
        a0.y += bf2f(v0.y) + bf2f(v1.y);
        a0.z += bf2f(v0.z) + bf2f(v1.z);
        a0.w += bf2f(v0.w) + bf2f(v1.w);
        e += 2;
    }
    if (e < end) {
        const ushort4 v0 = *(const ushort4*)(Y + (size_t)col[e] * 256 + c4);
        a0.x += bf2f(v0.x); a0.y += bf2f(v0.y);
        a0.z += bf2f(v0.z); a0.w += bf2f(v0.w);
    }
    float4 acc;
    acc.x = a0.x + a1.x; acc.y = a0.y + a1.y;
    acc.z = a0.z + a1.z; acc.w = a0.w + a1.w;

    const float inv = 1.0f / fmaxf((float)deg, 1.0f);
    float4 o;
    o.x = acc.x * inv + z.x;
    o.y = acc.y * inv + z.y;
    o.z = acc.z * inv + z.z;
    o.w = acc.w * inv + z.w;
    if (LAYER1) {
        o.x = fmaxf(o.x, 0.f); o.y = fmaxf(o.y, 0.f);
        o.z = fmaxf(o.z, 0.f); o.w = fmaxf(o.w, 0.f);
        ushort4 ob;
        ob.x = f2bf(o.x); ob.y = f2bf(o.y); ob.z = f2bf(o.z); ob.w = f2bf(o.w);
        *(ushort4*)((unsigned short*)OUT + (size_t)w * 256 + c4) = ob;
    } else {
        *(float4*)((float*)OUT + (size_t)w * 256 + c4) = o;
    }
}

// ---------------------------------------------------------------------------
extern "C" void kernel_launch(void* const* d_in, const int* in_sizes, int n_in,
                              void* d_out, int out_size, void* d_ws, size_t ws_size,
                              hipStream_t stream) {
    const float* x   = (const float*)d_in[0];
    const void*  ei  = d_in[1];
    const float* W1l = (const float*)d_in[2];
    const float* b1  = (const float*)d_in[3];
    const float* W1r = (const float*)d_in[4];
    const float* W2l = (const float*)d_in[5];
    const float* b2  = (const float*)d_in[6];
    const float* W2r = (const float*)d_in[7];

    const int N = in_sizes[0] / IN_CH;  // 100000
    const int E = in_sizes[1] / 2;      // 1000000

    char* ws = (char*)d_ws;
    size_t off = 0;
    auto alloc = [&](size_t bytes) {
        void* p = ws + off;
        off = (off + bytes + 255) & ~(size_t)255;
        return p;
    };
    int* flag    = (int*)alloc(4);
    int* cnt     = (int*)alloc((size_t)(N + 1) * 4);  // [N] counts + [1] counter
    int* counter = cnt + N;
    int* beg     = (int*)alloc((size_t)N * 4);
    int* cur     = (int*)alloc((size_t)N * 4);
    int* col     = (int*)alloc((size_t)E * 4);
    unsigned short* wt1 = (unsigned short*)alloc((size_t)512 * 320 * 2);
    unsigned short* wt2 = (unsigned short*)alloc((size_t)512 * 256 * 2);
    unsigned short* xb  = (unsigned short*)alloc((size_t)N * 320 * 2);  // x bf16; hb reuses
    unsigned short* y   = (unsigned short*)alloc((size_t)N * 256 * 2);  // y bf16

    unsigned short* hb = xb;  // h bf16 [N][256]; xb dead after layer-1 GEMM

    float* out = (float*)d_out;
    unsigned short* z1 = (unsigned short*)d_out;  // layer-1 z bf16, dense rows (256)
    unsigned short* z2 = (unsigned short*)d_out;  // layer-2 z bf16, stride 512

    // ---- CSR build (by dst, unordered groups) ----
    hipMemsetAsync(cnt, 0, (size_t)(N + 1) * 4, stream);
    detect_idx_kernel<<<1, 64, 0, stream>>>(ei, flag);
    hist_kernel<<<(E + 255) / 256, 256, 0, stream>>>(ei, flag, cnt, E);
    offsets_kernel<<<(N + 255) / 256, 256, 0, stream>>>(cnt, counter, beg, cur, N);
    fill_kernel<<<(E + 255) / 256, 256, 0, stream>>>(ei, flag, cur, col, E);

    // ---- conversions ----
    convert_x_kernel<<<(N * 40 + 255) / 256, 256, 0, stream>>>(x, xb, N);
    convert_w_kernel<<<(512 * 320 + 255) / 256, 256, 0, stream>>>(W1l, W1r, wt1, IN_CH, 320);
    convert_w_kernel<<<(512 * 256 + 255) / 256, 256, 0, stream>>>(W2l, W2r, wt2, HID, 256);

    const dim3 ggrid((N + 127) / 128, 2);  // y: 0=Y block, 1=Z block

    // ---- layer 1: y=x@W1l (bf16), z1(d_out,bf16)=x@W1r+b1 ; h=relu(mean+z1) ----
    mfma_gemm_kernel<320, 256><<<ggrid, 512, 0, stream>>>(xb, wt1, b1, y, z1, N);
    gather_agg_kernel<true><<<(N + 3) / 4, 256, 0, stream>>>(y, beg, cnt, col, z1, hb, N);

    // ---- layer 2: y=h@W2l, z2(d_out rows, bf16)=h@W2r+b2 ; out = mean+z2 (in place) ----
    mfma_gemm_kernel<256, 512><<<ggrid, 512, 0, stream>>>(hb, wt2, b2, y, z2, N);
    gather_agg_kernel<false><<<(N + 3) / 4, 256, 0, stream>>>(y, beg, cnt, col, z2, out, N);
}